// Round 4
// baseline (457.914 us; speedup 1.0000x reference)
//
#include <hip/hip_runtime.h>
#include <stdint.h>

// UnarySqrt scan, T=64 steps, N=2^20 channels, exact {0,1} floats.
//   per step: p = x*(1-tr); out = tr + p; tr' = p
// On {0,1} data: out = tr|x ; tr' = x & ~tr  (1-bit logic).
//
// R18: fully-flat 3-phase bit pipeline.
// Ledger: R14 single=153us, R15 split=143 (best), R16 fill-clone-expand=167
// (32x ws read amp), R17 fused t-split=161. All compute phases ~3.3-3.7 TB/s
// vs fill's 6.5. Shared property of ALL prior variants: column-chunk walks
// (every block revisits 64 rows at 4MB stride). R18 removes ALL strided HBM
// access:
//   A: flat row-major read sweep, ballot-pack bits -> 8MB ws   (pure read)
//   B: shfl 64x64 bit-transpose + u64 Kogge-Stone affine scan  (L3 only)
//      tr'=x&~tr is affine GF(2): tr=A^(B&T0); compose A^=B&(A<<d), B&=B<<d
//   C: fill-clone expand, single-touch packed reads            (pure write)
// Packing along N (not T) means each packed word is produced once and
// consumed once -- R16's amplification bug is structurally impossible.
// Predicted: A~45 B~8 C~42 -> dur 425 -> ~380-395. If A caps at ~3.3 TB/s
// (dur ~405-415), flat reads hit the same wall => genuine read ceiling =>
// roofline next round.

typedef float v4f __attribute__((ext_vector_type(4)));
typedef unsigned long long u64;

// Packed layout (both P and Q): word index (s*4 + k)*64 + t,
//   bit l = value at row t, float column s*256 + 4*l + k.
// P = input bits, Q = output bits. nseg = N/256.

// ---------------------------------------------------------------- phase A
// Pure flat read. Wave-task = (t, s): lane l loads v4f at columns
// s*256+4l..+3 (1 KB contiguous per wave), 4 ballots, 4 lanes store 8B each.
__global__ __launch_bounds__(256) void UnarySqrt_packA(
    const v4f* __restrict__ in, u64* __restrict__ P, int nseg)
{
    const int l = threadIdx.x & 63;
    const int wid = threadIdx.x >> 6;
    const int stride_v4 = nseg * 64;
    const int ntask = 64 * nseg;
    const int nwave = gridDim.x * 4;

    for (int task = blockIdx.x * 4 + wid; task < ntask; task += nwave) {
        const int t = task / nseg;
        const int s = task - t * nseg;
        v4f x = in[(size_t)t * stride_v4 + s * 64 + l];
        u64 b0 = __ballot(x[0] != 0.0f);
        u64 b1 = __ballot(x[1] != 0.0f);
        u64 b2 = __ballot(x[2] != 0.0f);
        u64 b3 = __ballot(x[3] != 0.0f);
        if (l < 4) {
            u64 w = (l == 0) ? b0 : (l == 1) ? b1 : (l == 2) ? b2 : b3;
            P[((size_t)s * 4 + l) * 64 + t] = w;
        }
    }
}

// ---------------------------------------------------------------- phase B
// 64x64 bit transpose across lanes: lane r holds word w (bit c); result
// lane r holds bit c = orig(c, r). Classic recursive block swap via shfl.
__device__ __forceinline__ u64 xpose64(u64 w, const int lane)
{
    u64 t;
    t = __shfl_xor(w, 32);
    w = (lane & 32) ? ((w & 0xFFFFFFFF00000000ull) | ((t & 0xFFFFFFFF00000000ull) >> 32))
                    : ((w & 0x00000000FFFFFFFFull) | ((t & 0x00000000FFFFFFFFull) << 32));
    t = __shfl_xor(w, 16);
    w = (lane & 16) ? ((w & 0xFFFF0000FFFF0000ull) | ((t & 0xFFFF0000FFFF0000ull) >> 16))
                    : ((w & 0x0000FFFF0000FFFFull) | ((t & 0x0000FFFF0000FFFFull) << 16));
    t = __shfl_xor(w, 8);
    w = (lane & 8)  ? ((w & 0xFF00FF00FF00FF00ull) | ((t & 0xFF00FF00FF00FF00ull) >> 8))
                    : ((w & 0x00FF00FF00FF00FFull) | ((t & 0x00FF00FF00FF00FFull) << 8));
    t = __shfl_xor(w, 4);
    w = (lane & 4)  ? ((w & 0xF0F0F0F0F0F0F0F0ull) | ((t & 0xF0F0F0F0F0F0F0F0ull) >> 4))
                    : ((w & 0x0F0F0F0F0F0F0F0Full) | ((t & 0x0F0F0F0F0F0F0F0Full) << 4));
    t = __shfl_xor(w, 2);
    w = (lane & 2)  ? ((w & 0xCCCCCCCCCCCCCCCCull) | ((t & 0xCCCCCCCCCCCCCCCCull) >> 2))
                    : ((w & 0x3333333333333333ull) | ((t & 0x3333333333333333ull) << 2));
    t = __shfl_xor(w, 1);
    w = (lane & 1)  ? ((w & 0xAAAAAAAAAAAAAAAAull) | ((t & 0xAAAAAAAAAAAAAAAAull) >> 1))
                    : ((w & 0x5555555555555555ull) | ((t & 0x5555555555555555ull) << 1));
    return w;
}

// Affine scan over bits of X (bit t = x_t): tr_0 = T0, tr_t = x_{t-1}&~tr_{t-1}.
// (a,b) transfer: tr_t = A_t ^ (B_t & T0). Kogge-Stone doubling.
// Returns OUT word: bit t = x_t | tr_t.   (verified: X=1 -> out=0b011; X=0b111 -> 0b1111)
__device__ __forceinline__ u64 scan_sel(u64 X, u64 T0mask)
{
    u64 A = X << 1;
    u64 B = A | 1ull;
    #pragma unroll
    for (int i = 0; i < 6; ++i) {
        const int d = 1 << i;
        u64 Ash = A << d;
        u64 Bsh = (B << d) | ((1ull << d) - 1ull);
        A ^= (B & Ash);
        B &= Bsh;
    }
    return X | (A ^ (B & T0mask));
}

__global__ __launch_bounds__(256) void UnarySqrt_scanB(
    const u64* __restrict__ P, const v4f* __restrict__ trace0,
    u64* __restrict__ Q, int nseg)
{
    const int lane = threadIdx.x & 63;   // role 1: t index; role 2 (post-xpose): column l
    const int k = threadIdx.x >> 6;      // component 0..3

    for (int s = blockIdx.x; s < nseg; s += gridDim.x) {
        u64 w = P[((size_t)s * 4 + k) * 64 + lane];      // coalesced 512B/wave
        w = xpose64(w, lane);                            // lane l: bit t = x_t of col s*256+4l+k
        v4f t0 = trace0[s * 64 + lane];                  // coalesced 1KB/wave
        u64 T0mask = (t0[k] != 0.0f) ? ~0ull : 0ull;
        w = scan_sel(w, T0mask);                         // bit t = out_t
        w = xpose64(w, lane);                            // back: lane t, bit l
        Q[((size_t)s * 4 + k) * 64 + lane] = w;          // coalesced 512B/wave
    }
}

// ---------------------------------------------------------------- phase C
// Pure flat write. Block-task = (t, sc): 4 segments, 16 broadcast u64 loads
// (L2/L3-hot, single logical touch), one 4 KB contiguous store.
__global__ __launch_bounds__(256) void UnarySqrt_expandC(
    const u64* __restrict__ Q, v4f* __restrict__ out, int nseg)
{
    const int nsc = nseg >> 2;            // segment-chunks per row
    const int ntask = 64 * nsc;
    const int l = threadIdx.x & 63;
    const int sl = threadIdx.x >> 6;
    const int stride_v4 = nseg * 64;

    for (int bid = blockIdx.x; bid < ntask; bid += gridDim.x) {
        const int t = bid / nsc;
        const int sc = bid - t * nsc;
        const int s = sc * 4 + sl;
        const u64* q = &Q[(size_t)s * 256 + t];
        u64 w0 = q[0], w1 = q[64], w2 = q[128], w3 = q[192];
        v4f o;
        o[0] = (float)((w0 >> l) & 1ull);
        o[1] = (float)((w1 >> l) & 1ull);
        o[2] = (float)((w2 >> l) & 1ull);
        o[3] = (float)((w3 >> l) & 1ull);
        out[(size_t)t * stride_v4 + (size_t)sc * 256 + threadIdx.x] = o;
    }
}

// -------------------------------------------------- fallback: single pass
// (R14 best single-kernel structure — correct for T==64 without workspace.)
__global__ __launch_bounds__(1024) void UnarySqrt_kernel(
    const v4f* __restrict__ in, const v4f* __restrict__ trace0,
    v4f* __restrict__ out, int stride)
{
    const int idx = blockIdx.x * blockDim.x + threadIdx.x;
    if (idx >= stride) return;

    v4f tr = trace0[idx];
    v4f x  = __builtin_nontemporal_load(&in[idx]);

    #pragma unroll 8
    for (int t = 0; t < 64; ++t) {
        v4f xn;
        if (t + 1 < 64) {
            xn = __builtin_nontemporal_load(
                &in[(size_t)(t + 1) * (size_t)stride + (size_t)idx]);
        }
        v4f p = x * (1.0f - tr);
        v4f o = tr + p;
        out[(size_t)t * (size_t)stride + (size_t)idx] = o;
        tr = p;
        x = xn;
    }
}

// Generic fallback (correct for any T, N%4==0, arbitrary float inputs).
__global__ __launch_bounds__(256) void UnarySqrt_generic(
    const v4f* __restrict__ in, const v4f* __restrict__ trace0,
    v4f* __restrict__ out, int stride, int T)
{
    int idx = blockIdx.x * blockDim.x + threadIdx.x;
    if (idx >= stride) return;
    v4f tr = trace0[idx];
    for (int t = 0; t < T; ++t) {
        v4f x = in[(size_t)t * stride + idx];
        v4f p = x * (1.0f - tr);
        out[(size_t)t * stride + idx] = tr + p;
        tr = p;
    }
}

extern "C" void kernel_launch(void* const* d_in, const int* in_sizes, int n_in,
                              void* d_out, int out_size, void* d_ws, size_t ws_size,
                              hipStream_t stream) {
    const float* bits   = (const float*)d_in[0];  // [T, N]
    const float* trace0 = (const float*)d_in[1];  // [N]

    int N = in_sizes[1];
    int T = in_sizes[0] / N;
    int stride = N / 4;

    int nseg = N / 256;
    size_t ws_needed = (size_t)nseg * 4096;       // P + Q, 16 MB at N=2^20

    if (T == 64 && (N % 1024) == 0 && d_ws && ws_size >= ws_needed) {
        u64* P = (u64*)d_ws;
        u64* Q = P + (size_t)nseg * 256;

        UnarySqrt_packA<<<2048, 256, 0, stream>>>(
            (const v4f*)bits, P, nseg);                       // 32 waves/CU
        int bgrid = nseg < 4096 ? nseg : 4096;
        UnarySqrt_scanB<<<bgrid, 256, 0, stream>>>(
            P, (const v4f*)trace0, Q, nseg);
        UnarySqrt_expandC<<<16384, 256, 0, stream>>>(
            Q, (v4f*)d_out, nseg);
    } else if (T == 64 && (stride % 1024) == 0) {
        int grid = stride / 1024;
        UnarySqrt_kernel<<<grid, 1024, 0, stream>>>(
            (const v4f*)bits, (const v4f*)trace0, (v4f*)d_out, stride);
    } else {
        int block = 256;
        int grid = (stride + block - 1) / block;
        UnarySqrt_generic<<<grid, block, 0, stream>>>(
            (const v4f*)bits, (const v4f*)trace0, (v4f*)d_out, stride, T);
    }
}

// Round 6
// 450.871 us; speedup vs baseline: 1.0156x; 1.0156x over previous
//
#include <hip/hip_runtime.h>
#include <stdint.h>

// UnarySqrt scan, T=64 steps, N=2^20 channels, exact {0,1} floats.
//   per step: p = x*(1-tr); out = tr + p; tr' = p
// On {0,1} data this is 1-bit logic: out = tr|x ; tr' = x & ~tr.
//
// R20: RESUBMIT of R19 (= R15, measured best 425.0 us). R5's bench was an
// infra failure ("MI355X container failed twice") -- no kernel signal.
// Session ledger:
//   R14 single mixed            435.5
//   R15 split pack/expand       425.0  <- this kernel
//   R16 fill-clone expand       449.1  (32x ws read amplification)
//   R17 fused t-split full-occ  443.5  (occupancy not the bottleneck)
//   R18 flat 3-phase ballot     457.9  (fragmented 8B packed stores)
// Falsified mechanisms: MLP/latency (R15 pack holds ~128KB/CU in flight,
// far above the latency-BW product), occupancy (R17), stream purity (+10us
// only), access flatness (R16/R18 negative), cache hints (R0 inert), byte
// reduction (516MB compulsory). In-graph aggregate for ANY r+w compute
// kernel: ~2.4-3.5 TB/s across 19 variants; write-only fill: 6.5 TB/s.
// If this reproduces ~425, remaining dur = fill(165, harness) +
// restore(~100, harness) + ~145us kernel at the structure-independent
// in-graph rate => roofline.

typedef float v4f __attribute__((ext_vector_type(4)));
typedef uint32_t v4u __attribute__((ext_vector_type(4)));

// ---------------------------------------------------------------- phase 1
// Pure-read pass: scan + pack. ws_lo[idx] = bits t=0..31 of the 4 columns
// in v4f-group idx; ws_hi[idx] = bits t=32..63.
__global__ __launch_bounds__(1024) void UnarySqrt_pack(
    const v4f* __restrict__ in,      // [64, stride]
    const v4f* __restrict__ trace0,  // [stride]
    v4u* __restrict__ ws_lo,         // [stride]
    v4u* __restrict__ ws_hi,         // [stride]
    int stride)
{
    const int idx = blockIdx.x * blockDim.x + threadIdx.x;
    if (idx >= stride) return;

    v4f t0 = trace0[idx];
    uint32_t tr[4];
    #pragma unroll
    for (int j = 0; j < 4; ++j) tr[j] = (t0[j] != 0.0f) ? 1u : 0u;

    v4u lo = {0u, 0u, 0u, 0u};
    #pragma unroll 8
    for (int t = 0; t < 32; ++t) {
        v4f x = in[(size_t)t * (size_t)stride + (size_t)idx];
        #pragma unroll
        for (int j = 0; j < 4; ++j) {
            uint32_t xb = (x[j] != 0.0f) ? 1u : 0u;
            lo[j] |= (xb | tr[j]) << t;      // out bit
            tr[j] = xb & (tr[j] ^ 1u);       // JKFF: J=out, K=1
        }
    }
    v4u hi = {0u, 0u, 0u, 0u};
    #pragma unroll 8
    for (int t = 32; t < 64; ++t) {
        v4f x = in[(size_t)t * (size_t)stride + (size_t)idx];
        #pragma unroll
        for (int j = 0; j < 4; ++j) {
            uint32_t xb = (x[j] != 0.0f) ? 1u : 0u;
            hi[j] |= (xb | tr[j]) << (t - 32);
            tr[j] = xb & (tr[j] ^ 1u);
        }
    }
    ws_lo[idx] = lo;   // 8 MB total; stays dirty in L2/L3 for phase 2
    ws_hi[idx] = hi;
}

// ---------------------------------------------------------------- phase 2
// Write-dominant pass: read packed bits (cache-resident), expand to floats.
__global__ __launch_bounds__(1024) void UnarySqrt_expand(
    const v4u* __restrict__ ws_lo,
    const v4u* __restrict__ ws_hi,
    v4f* __restrict__ out,           // [64, stride]
    int stride)
{
    const int idx = blockIdx.x * blockDim.x + threadIdx.x;
    if (idx >= stride) return;

    v4u lo = ws_lo[idx];
    v4u hi = ws_hi[idx];

    #pragma unroll 8
    for (int t = 0; t < 32; ++t) {
        v4f o;
        #pragma unroll
        for (int j = 0; j < 4; ++j)
            o[j] = ((lo[j] >> t) & 1u) ? 1.0f : 0.0f;
        out[(size_t)t * (size_t)stride + (size_t)idx] = o;
    }
    #pragma unroll 8
    for (int t = 32; t < 64; ++t) {
        v4f o;
        #pragma unroll
        for (int j = 0; j < 4; ++j)
            o[j] = ((hi[j] >> (t - 32)) & 1u) ? 1.0f : 0.0f;
        out[(size_t)t * (size_t)stride + (size_t)idx] = o;
    }
}

// -------------------------------------------------- fallback: single pass
// (R14 best single-kernel structure — correct for T==64 without workspace.)
__global__ __launch_bounds__(1024) void UnarySqrt_kernel(
    const v4f* __restrict__ in, const v4f* __restrict__ trace0,
    v4f* __restrict__ out, int stride)
{
    const int idx = blockIdx.x * blockDim.x + threadIdx.x;
    if (idx >= stride) return;

    v4f tr = trace0[idx];
    v4f x  = __builtin_nontemporal_load(&in[idx]);

    #pragma unroll 8
    for (int t = 0; t < 64; ++t) {
        v4f xn;
        if (t + 1 < 64) {
            xn = __builtin_nontemporal_load(
                &in[(size_t)(t + 1) * (size_t)stride + (size_t)idx]);
        }
        v4f p = x * (1.0f - tr);
        v4f o = tr + p;
        out[(size_t)t * (size_t)stride + (size_t)idx] = o;
        tr = p;
        x = xn;
    }
}

// Generic fallback (correct for any T, N%4==0, arbitrary float inputs).
__global__ __launch_bounds__(256) void UnarySqrt_generic(
    const v4f* __restrict__ in, const v4f* __restrict__ trace0,
    v4f* __restrict__ out, int stride, int T)
{
    int idx = blockIdx.x * blockDim.x + threadIdx.x;
    if (idx >= stride) return;
    v4f tr = trace0[idx];
    for (int t = 0; t < T; ++t) {
        v4f x = in[(size_t)t * stride + idx];
        v4f p = x * (1.0f - tr);
        out[(size_t)t * stride + idx] = tr + p;
        tr = p;
    }
}

extern "C" void kernel_launch(void* const* d_in, const int* in_sizes, int n_in,
                              void* d_out, int out_size, void* d_ws, size_t ws_size,
                              hipStream_t stream) {
    const float* bits   = (const float*)d_in[0];  // [T, N]
    const float* trace0 = (const float*)d_in[1];  // [N]

    int N = in_sizes[1];
    int T = in_sizes[0] / N;
    int stride = N / 4;

    size_t ws_needed = (size_t)stride * 2 * sizeof(v4u);  // 8 MB at N=2^20

    if (T == 64 && (stride % 1024) == 0 && d_ws && ws_size >= ws_needed) {
        int grid = stride / 1024;  // 256 blocks at N=2^20
        v4u* ws_lo = (v4u*)d_ws;
        v4u* ws_hi = ws_lo + stride;
        UnarySqrt_pack<<<grid, 1024, 0, stream>>>(
            (const v4f*)bits, (const v4f*)trace0, ws_lo, ws_hi, stride);
        UnarySqrt_expand<<<grid, 1024, 0, stream>>>(
            ws_lo, ws_hi, (v4f*)d_out, stride);
    } else if (T == 64 && (stride % 1024) == 0) {
        int grid = stride / 1024;
        UnarySqrt_kernel<<<grid, 1024, 0, stream>>>(
            (const v4f*)bits, (const v4f*)trace0, (v4f*)d_out, stride);
    } else {
        int block = 256;
        int grid = (stride + block - 1) / block;
        UnarySqrt_generic<<<grid, block, 0, stream>>>(
            (const v4f*)bits, (const v4f*)trace0, (v4f*)d_out, stride, T);
    }
}